// Round 3
// baseline (596.746 us; speedup 1.0000x reference)
//
#include <hip/hip_runtime.h>

#define B_ 16
#define C_ 512
#define S_ 128
#define T_ 2048
#define HALF 18
#define WLEN 37

typedef __bf16 bf16x8 __attribute__((ext_vector_type(8)));
typedef float f32x4 __attribute__((ext_vector_type(4)));
typedef float f32x16 __attribute__((ext_vector_type(16)));
typedef unsigned short ushort_t;

__device__ inline ushort_t f2bf(float x) {
    unsigned u = __float_as_uint(x);
    u += 0x7fffu + ((u >> 16) & 1u);  // RNE; inputs are finite
    return (ushort_t)(u >> 16);
}
__device__ inline float bf2f(ushort_t h) {
    return __uint_as_float(((unsigned)h) << 16);
}
__device__ inline float fast_tanh(float z) {
    // tanh(z) = 1 - 2/(exp(2z)+1); |rel err| ~1e-6, fine vs 7.7e-2 threshold
    float e = __expf(2.f * z);
    return 1.f - __fdividef(2.f, e + 1.f);
}

#define MFMA16(a, b, c) __builtin_amdgcn_mfma_f32_16x16x32_bf16((a), (b), (c), 0, 0, 0)
#define MFMA32(a, b, c) __builtin_amdgcn_mfma_f32_32x32x16_bf16((a), (b), (c), 0, 0, 0)

// ---------------- weight prep: fp32 -> bf16 (+ conv relayout to [o][tap*512+i]) --
__global__ void prep_weights(const float* __restrict__ fc1, const float* __restrict__ fc2,
                             const float* __restrict__ c1, const float* __restrict__ c2,
                             ushort_t* __restrict__ Wfc, ushort_t* __restrict__ Wc1,
                             ushort_t* __restrict__ Wc2) {
    const int n_fc = 1024 * 128;
    const int n_c = 512 * 1536;
    const int total = 2 * n_fc + 2 * n_c;
    for (int idx = blockIdx.x * blockDim.x + threadIdx.x; idx < total;
         idx += gridDim.x * blockDim.x) {
        if (idx < n_fc) {
            Wfc[idx] = f2bf(fc1[idx]);
        } else if (idx < 2 * n_fc) {
            Wfc[idx] = f2bf(fc2[idx - n_fc]);
        } else {
            int r = idx - 2 * n_fc;
            const float* src = c1;
            ushort_t* dst = Wc1;
            if (r >= n_c) { r -= n_c; src = c2; dst = Wc2; }
            int o = r / 1536;
            int rem = r - o * 1536;
            int k = rem >> 9;        // tap 0..2
            int i = rem & 511;       // in-channel
            dst[o * 1536 + (k << 9) + i] = f2bf(src[(o * 512 + i) * 3 + k]);
        }
    }
}

// ---------------- zero the halo rows (t=-1, t=T) of both padded buffers --------
__global__ void zero_pads(ushort_t* __restrict__ y1p, ushort_t* __restrict__ y2p) {
    int tid = blockIdx.x * blockDim.x + threadIdx.x;
    if (tid < 4096) {
        ushort_t* base = (tid & 1) ? y2p : y1p;
        int r = tid >> 1;                 // 0..2047
        int bb = r >> 7;                  // batch
        int rowsel = (r >> 6) & 1;        // 0: t=-1 row, 1: t=T row
        int col = (r & 63) * 8;
        size_t row = (size_t)bb * (T_ + 2) + (rowsel ? (T_ + 1) : 0);
        *(uint4*)&base[row * C_ + col] = (uint4){0, 0, 0, 0};
    }
}

// ---------------- win_sum(s) over t, output transposed: sw_t[b][t][s] bf16 ------
__global__ __launch_bounds__(256) void winsum_kernel(const float* __restrict__ s,
                                                     ushort_t* __restrict__ sw_t) {
    int b = blockIdx.y;
    int t0 = blockIdx.x * 64;
    __shared__ float sb[128][101];
    int tid = threadIdx.x;
    for (int e = tid; e < 128 * 100; e += 256) {
        int sj = e / 100;
        int u = e - sj * 100;
        int gt = t0 - HALF + u;
        float v = 0.f;
        if (gt >= 0 && gt < T_) v = s[((size_t)(b * S_ + sj)) * T_ + gt];
        sb[sj][u] = v;
    }
    __syncthreads();
    for (int e = tid; e < 64 * 128; e += 256) {
        int tl = e >> 7;
        int sj = e & 127;
        float sum = 0.f;
#pragma unroll
        for (int d = 0; d < WLEN; ++d) sum += sb[sj][tl + d];
        sw_t[((size_t)(b * T_ + t0 + tl)) * S_ + sj] = f2bf(sum);
    }
}

// ---------------- fused adawin instance + leaky-relu ----------------------------
// Output: padded [b][T+2][c] bf16, coalesced via LDS transpose.
// INLAYOUT 0: x is fp32 [b][c][t].  INLAYOUT 1: x is bf16 padded [b][T+2][c].
template <int INLAYOUT>
__global__ __launch_bounds__(256) void adawin_kernel(
    const void* __restrict__ xin_, const ushort_t* __restrict__ sw_t,
    const ushort_t* __restrict__ Wfc, const float* __restrict__ fcb,
    const float* __restrict__ alpha, const int* __restrict__ lengths,
    ushort_t* __restrict__ youtp) {
    int t0 = blockIdx.x * 64;
    int c0 = blockIdx.y * 64;
    int b = blockIdx.z;
    __shared__ __attribute__((aligned(16))) ushort_t smem[128 * 136 + 64 * 136];
    ushort_t (*As)[136] = (ushort_t(*)[136])smem;
    ushort_t (*Bs)[136] = (ushort_t(*)[136])(smem + 128 * 136);
    int tid = threadIdx.x;

    {  // stage A: rows 0..63 = Wfc[c0..] (gamma), 64..127 = Wfc[512+c0..] (beta)
        int r = tid >> 4;
        int cseg = (tid & 15) * 8;
#pragma unroll
        for (int p = 0; p < 8; ++p) {
            int row = p * 16 + r;
            int grow = (row < 64) ? (c0 + row) : (448 + c0 + row);
            *(uint4*)&As[row][cseg] = *(const uint4*)&Wfc[(size_t)grow * 128 + cseg];
        }
    }
    {  // stage B: sw_t rows are s-contiguous
        int tl = tid & 63;
        int sg = tid >> 6;
        const ushort_t* src = &sw_t[((size_t)(b * T_ + t0 + tl)) * S_];
#pragma unroll
        for (int j = 0; j < 4; ++j) {
            int col = sg * 32 + j * 8;
            *(uint4*)&Bs[tl][col] = *(const uint4*)&src[col];
        }
    }
    __syncthreads();

    int wave = tid >> 6, lane = tid & 63;
    int quad = lane >> 4, l = lane & 15;
    f32x4 accg[4], accb[4];
#pragma unroll
    for (int n = 0; n < 4; ++n) {
        accg[n] = (f32x4){0.f, 0.f, 0.f, 0.f};
        accb[n] = (f32x4){0.f, 0.f, 0.f, 0.f};
    }
    int rg = wave * 16 + l;
    int rb = 64 + wave * 16 + l;
#pragma unroll
    for (int ks = 0; ks < 4; ++ks) {
        int kc = ks * 32 + quad * 8;
        bf16x8 ag = *(const bf16x8*)&As[rg][kc];
        bf16x8 ab = *(const bf16x8*)&As[rb][kc];
#pragma unroll
        for (int n = 0; n < 4; ++n) {
            bf16x8 bb = *(const bf16x8*)&Bs[n * 16 + l][kc];
            accg[n] = MFMA16(ag, bb, accg[n]);
            accb[n] = MFMA16(ab, bb, accb[n]);
        }
    }

    __syncthreads();  // all waves done reading As/Bs; Ts overlays As
    ushort_t (*Ts)[72] = (ushort_t(*)[72])smem;

    int len = lengths[b];
    float alph = alpha[0];
    const float* xf = (const float*)xin_;
    const ushort_t* xh = (const ushort_t*)xin_;
    int clocal = wave * 16 + quad * 4;
    int cbase = c0 + clocal;
#pragma unroll
    for (int n = 0; n < 4; ++n) {
        int t = t0 + n * 16 + l;
        int lo = t - HALF; if (lo < 0) lo = 0;
        int hi = t + HALF; if (hi > T_ - 1) hi = T_ - 1;
        float cnt = (float)(hi - lo + 1);
        int hv = hi < (len - 1) ? hi : (len - 1);
        int mdi = hv - lo + 1; if (mdi < 0) mdi = 0;
        float m = (t < len) ? 1.f : 0.f;
        float sc = m / ((float)mdi + 1e-9f);

        float xv[4];
        if (INLAYOUT == 0) {
#pragma unroll
            for (int j = 0; j < 4; ++j)
                xv[j] = xf[(size_t)(b * C_ + cbase + j) * T_ + t];
        } else {
            uint2 xraw = *(const uint2*)&xh[((size_t)(b * (T_ + 2) + 1 + t)) * C_ + cbase];
            xv[0] = bf2f((ushort_t)(xraw.x & 0xffff));
            xv[1] = bf2f((ushort_t)(xraw.x >> 16));
            xv[2] = bf2f((ushort_t)(xraw.y & 0xffff));
            xv[3] = bf2f((ushort_t)(xraw.y >> 16));
        }
        unsigned pk[2];
#pragma unroll
        for (int j = 0; j < 4; ++j) {
            int c = cbase + j;
            float gamma = (accg[n][j] + fcb[c] * cnt) * sc;
            float beta = (accb[n][j] + fcb[C_ + c] * cnt) * sc;
            float xn = fast_tanh(alph * xv[j]);
            float v = (1.f + gamma) * xn + beta;
            v = v > 0.f ? v : 0.2f * v;
            unsigned hv16 = (unsigned)f2bf(v);
            if (j & 1) pk[j >> 1] |= hv16 << 16;
            else pk[j >> 1] = hv16;
        }
        *(uint2*)&Ts[n * 16 + l][clocal] = (uint2){pk[0], pk[1]};
    }
    __syncthreads();
    {  // coalesced copy-out: 64 rows x 64 c; 4 threads/row, 32 B each
        int row = tid >> 2;
        int seg = (tid & 3) * 16;
        size_t gbase = ((size_t)(b * (T_ + 2) + 1 + t0 + row)) * C_ + c0 + seg;
        *(uint4*)&youtp[gbase] = *(const uint4*)&Ts[row][seg];
        *(uint4*)&youtp[gbase + 8] = *(const uint4*)&Ts[row][seg + 8];
    }
}

// ---------------- conv1d k=3 as implicit MFMA GEMM (32x32x16, [t][c] layout) ----
// Block tile 128o x 128t, 4 waves (64o x 64t each). Register-prefetch pipeline:
// chunk ch+1's global loads issue before chunk ch's MFMA, hiding VMEM latency.
// EPI 0: out = acc + bias -> bf16 padded [b][T+2][c] (LDS-transposed stores)
// EPI 1: out = (acc + bias + x) / sqrt(2) -> fp32 [b][c][t] (final)
template <int EPI>
__global__ __launch_bounds__(256, 3) void conv_kernel(
    const ushort_t* __restrict__ Xp, const ushort_t* __restrict__ Wc,
    const float* __restrict__ bias, const float* __restrict__ resid,
    ushort_t* __restrict__ out_bf, float* __restrict__ out_f) {
    int t0 = blockIdx.x * 128;
    int o0 = blockIdx.y * 128;
    int b = blockIdx.z;
    __shared__ __attribute__((aligned(16))) ushort_t smem[128 * 104 + 130 * 56];
    ushort_t (*As)[104] = (ushort_t(*)[104])smem;            // [o][tap*32+k]
    ushort_t (*Bs)[56] = (ushort_t(*)[56])(smem + 128 * 104); // [t+halo][k]
    int tid = threadIdx.x;
    int lane = tid & 63, wave = tid >> 6;
    int l32 = lane & 31, khalf = lane >> 5;
    int wo = (wave & 1) * 64, wt = (wave >> 1) * 64;

    // ---- staging maps (precomputed; per-chunk just +32 elements) ----
    // A: row = tid>>1, segs (tid&1)*6+p; elem offsets tap*512+kk
    const int soE[6] = {0, 8, 16, 24, 512, 520};
    const int soO[6] = {528, 536, 1024, 1032, 1040, 1048};
    int odd = tid & 1;
    int arow = tid >> 1;
    const ushort_t* abase = Wc + (size_t)(o0 + arow) * 1536;
    const ushort_t* ap[6];
    ushort_t* al[6];
#pragma unroll
    for (int p = 0; p < 6; ++p) {
        ap[p] = abase + (odd ? soO[p] : soE[p]);
        al[p] = &As[arow][odd * 48 + p * 8];
    }
    const ushort_t* xbase = Xp + (size_t)(b * (T_ + 2) + t0) * C_;  // row r <-> t0-1+r
    const ushort_t* bp01 = xbase + (size_t)(tid >> 1) * C_ + odd * 16;
    ushort_t* bl01 = &Bs[tid >> 1][odd * 16];
    const ushort_t* bp2 = xbase + (size_t)(128 + (tid >> 2)) * C_ + (tid & 3) * 8;
    ushort_t* bl2 = &Bs[128 + (tid >> 2)][(tid & 3) * 8];
    bool tail = tid < 8;

    uint4 ra[6], rbv[2], rt;
#pragma unroll
    for (int p = 0; p < 6; ++p) ra[p] = *(const uint4*)ap[p];
#pragma unroll
    for (int p = 0; p < 2; ++p) rbv[p] = *(const uint4*)(bp01 + p * 8);
    if (tail) rt = *(const uint4*)bp2;

    f32x16 acc[2][2];
#pragma unroll
    for (int io = 0; io < 2; ++io)
#pragma unroll
        for (int it = 0; it < 2; ++it)
#pragma unroll
            for (int r = 0; r < 16; ++r) acc[io][it][r] = 0.f;

#pragma unroll 1
    for (int ch = 0; ch < 16; ++ch) {
        __syncthreads();  // previous compute done reading LDS
#pragma unroll
        for (int p = 0; p < 6; ++p) *(uint4*)al[p] = ra[p];
#pragma unroll
        for (int p = 0; p < 2; ++p) *(uint4*)(bl01 + p * 8) = rbv[p];
        if (tail) *(uint4*)bl2 = rt;
        __syncthreads();
        if (ch < 15) {  // prefetch next chunk; latency hides under MFMA below
            int off = (ch + 1) * 32;
#pragma unroll
            for (int p = 0; p < 6; ++p) ra[p] = *(const uint4*)(ap[p] + off);
#pragma unroll
            for (int p = 0; p < 2; ++p) rbv[p] = *(const uint4*)(bp01 + off + p * 8);
            if (tail) rt = *(const uint4*)(bp2 + off);
        }
#pragma unroll
        for (int tap = 0; tap < 3; ++tap) {
#pragma unroll
            for (int ks = 0; ks < 2; ++ks) {
                int kc = tap * 32 + ks * 16 + khalf * 8;
                bf16x8 a0 = *(const bf16x8*)&As[wo + l32][kc];
                bf16x8 a1 = *(const bf16x8*)&As[wo + 32 + l32][kc];
#pragma unroll
                for (int it = 0; it < 2; ++it) {
                    bf16x8 bb =
                        *(const bf16x8*)&Bs[wt + it * 32 + l32 + tap][ks * 16 + khalf * 8];
                    acc[0][it] = MFMA32(a0, bb, acc[0][it]);
                    acc[1][it] = MFMA32(a1, bb, acc[1][it]);
                }
            }
        }
    }

    // epilogue: C/D layout col=lane&31 (t), row=(reg&3)+8*(reg>>2)+4*khalf (o)
    if (EPI == 0) {
        ushort_t (*Ts)[136] = (ushort_t(*)[136])smem;  // [t][o], 128x136 fits in smem
        __syncthreads();
#pragma unroll
        for (int io = 0; io < 2; ++io)
#pragma unroll
            for (int it = 0; it < 2; ++it) {
                int trow = wt + it * 32 + l32;
#pragma unroll
                for (int g = 0; g < 4; ++g) {
                    int oc = wo + io * 32 + g * 8 + khalf * 4;
                    unsigned pk[2];
#pragma unroll
                    for (int j = 0; j < 4; ++j) {
                        float v = acc[io][it][g * 4 + j] + bias[o0 + oc + j];
                        unsigned hv16 = (unsigned)f2bf(v);
                        if (j & 1) pk[j >> 1] |= hv16 << 16;
                        else pk[j >> 1] = hv16;
                    }
                    *(uint2*)&Ts[trow][oc] = (uint2){pk[0], pk[1]};
                }
            }
        __syncthreads();
        int cc = (tid & 15) * 8;
        int rbse = tid >> 4;
#pragma unroll
        for (int j = 0; j < 8; ++j) {
            int row = j * 16 + rbse;
            *(uint4*)&out_bf[((size_t)(b * (T_ + 2) + 1 + t0 + row)) * C_ + o0 + cc] =
                *(const uint4*)&Ts[row][cc];
        }
    } else {
#pragma unroll
        for (int io = 0; io < 2; ++io)
#pragma unroll
            for (int it = 0; it < 2; ++it) {
                int obase = o0 + wo + io * 32;
                int t = t0 + wt + it * 32 + l32;
#pragma unroll
                for (int g = 0; g < 4; ++g) {
                    int oo = obase + g * 8 + khalf * 4;
#pragma unroll
                    for (int j = 0; j < 4; ++j) {
                        size_t off = (size_t)(b * C_ + oo + j) * T_ + t;
                        out_f[off] = (acc[io][it][g * 4 + j] + bias[oo + j] + resid[off]) *
                                     0.70710678118654752f;
                    }
                }
            }
    }
}

extern "C" void kernel_launch(void* const* d_in, const int* in_sizes, int n_in,
                              void* d_out, int out_size, void* d_ws, size_t ws_size,
                              hipStream_t stream) {
    const float* x = (const float*)d_in[0];
    const float* s = (const float*)d_in[1];
    const int* lengths = (const int*)d_in[2];
    const float* fc1_w = (const float*)d_in[3];
    const float* fc1_b = (const float*)d_in[4];
    const float* alpha1 = (const float*)d_in[5];
    const float* conv1_w = (const float*)d_in[6];
    const float* conv1_b = (const float*)d_in[7];
    const float* fc2_w = (const float*)d_in[8];
    const float* fc2_b = (const float*)d_in[9];
    const float* alpha2 = (const float*)d_in[10];
    const float* conv2_w = (const float*)d_in[11];
    const float* conv2_b = (const float*)d_in[12];

    char* ws = (char*)d_ws;
    ushort_t* sw_t = (ushort_t*)ws; ws += (size_t)B_ * T_ * S_ * 2;           // 8 MB
    ushort_t* Wfc = (ushort_t*)ws;  ws += (size_t)2 * 1024 * 128 * 2;         // 0.5 MB
    ushort_t* Wc1 = (ushort_t*)ws;  ws += (size_t)512 * 1536 * 2;             // 1.5 MB
    ushort_t* Wc2 = (ushort_t*)ws;  ws += (size_t)512 * 1536 * 2;             // 1.5 MB
    ushort_t* y1p = (ushort_t*)ws;  ws += (size_t)B_ * (T_ + 2) * C_ * 2;     // 33.6 MB
    ushort_t* y2p = (ushort_t*)ws;  ws += (size_t)B_ * (T_ + 2) * C_ * 2;     // 33.6 MB
    if ((size_t)(ws - (char*)d_ws) > ws_size) return;

    prep_weights<<<dim3(1024), dim3(256), 0, stream>>>(fc1_w, fc2_w, conv1_w, conv2_w,
                                                       Wfc, Wc1, Wc2);
    winsum_kernel<<<dim3(32, 16), dim3(256), 0, stream>>>(s, sw_t);
    zero_pads<<<dim3(16), dim3(256), 0, stream>>>(y1p, y2p);
    adawin_kernel<0><<<dim3(32, 8, 16), dim3(256), 0, stream>>>(
        (const void*)x, sw_t, Wfc, fc1_b, alpha1, lengths, y1p);
    conv_kernel<0><<<dim3(16, 4, 16), dim3(256), 0, stream>>>(
        y1p, Wc1, conv1_b, (const float*)nullptr, y2p, (float*)nullptr);
    adawin_kernel<1><<<dim3(32, 8, 16), dim3(256), 0, stream>>>(
        (const void*)y2p, sw_t, Wfc + 1024 * 128, fc2_b, alpha2, lengths, y1p);
    conv_kernel<1><<<dim3(16, 4, 16), dim3(256), 0, stream>>>(
        y1p, Wc2, conv2_b, x, (ushort_t*)nullptr, (float*)d_out);
}

// Round 4
// 357.141 us; speedup vs baseline: 1.6709x; 1.6709x over previous
//
#include <hip/hip_runtime.h>

#define B_ 16
#define C_ 512
#define S_ 128
#define T_ 2048
#define HALF 18
#define WLEN 37

typedef __bf16 bf16x8 __attribute__((ext_vector_type(8)));
typedef float f32x4 __attribute__((ext_vector_type(4)));
typedef float f32x16 __attribute__((ext_vector_type(16)));
typedef unsigned short ushort_t;

__device__ inline ushort_t f2bf(float x) {
    unsigned u = __float_as_uint(x);
    u += 0x7fffu + ((u >> 16) & 1u);  // RNE; inputs are finite
    return (ushort_t)(u >> 16);
}
__device__ inline float bf2f(ushort_t h) {
    return __uint_as_float(((unsigned)h) << 16);
}
__device__ inline float fast_tanh(float z) {
    float e = __expf(2.f * z);
    return 1.f - __fdividef(2.f, e + 1.f);
}
__device__ __forceinline__ void glds16(const void* g, void* l) {
    __builtin_amdgcn_global_load_lds(
        (const __attribute__((address_space(1))) unsigned*)g,
        (__attribute__((address_space(3))) unsigned*)l, 16, 0, 0);
}

#define MFMA16(a, b, c) __builtin_amdgcn_mfma_f32_16x16x32_bf16((a), (b), (c), 0, 0, 0)
#define MFMA32(a, b, c) __builtin_amdgcn_mfma_f32_32x32x16_bf16((a), (b), (c), 0, 0, 0)

// ---------------- fc weight prep: fp32 -> bf16 ----------------------------------
__global__ void prep_weights(const float* __restrict__ fc1, const float* __restrict__ fc2,
                             ushort_t* __restrict__ Wfc) {
    const int n_fc = 1024 * 128;
    int idx = blockIdx.x * blockDim.x + threadIdx.x;
    if (idx < n_fc) Wfc[idx] = f2bf(fc1[idx]);
    else if (idx < 2 * n_fc) Wfc[idx] = f2bf(fc2[idx - n_fc]);
}

// ---------------- conv weight images: pre-built LDS tiles for global_load_lds ---
// Image layout per conv: [oB(4)][ch(16)] x 26624 B. Each image IS the padded LDS
// A-tile [128 rows][13 granules of 16B]: granule g<12 -> tap=g>>2, cseg=g&3 holds
// w[o=oB*128+r][i=ch*32+cseg*8+e][tap]; g==12 is bank-conflict padding (zeros).
__global__ void prep_conv_images(const float* __restrict__ c1, const float* __restrict__ c2,
                                 ushort_t* __restrict__ I1, ushort_t* __restrict__ I2) {
    int idx = blockIdx.x * blockDim.x + threadIdx.x;  // granule id
    const int per_conv = 4 * 16 * 1664;               // 106496 granules
    if (idx >= 2 * per_conv) return;
    int conv = idx >= per_conv;
    int rr = conv ? idx - per_conv : idx;
    const float* src = conv ? c2 : c1;
    ushort_t* dst = conv ? I2 : I1;
    int blkch = rr / 1664;
    int G = rr - blkch * 1664;
    int r = G / 13;
    int g = G - r * 13;
    ushort_t vals[8];
    if (g == 12) {
#pragma unroll
        for (int e = 0; e < 8; ++e) vals[e] = 0;
    } else {
        int tap = g >> 2, seg = g & 3;
        int o = (blkch >> 4) * 128 + r;
        int chb = (blkch & 15) * 32 + seg * 8;
#pragma unroll
        for (int e = 0; e < 8; ++e)
            vals[e] = f2bf(src[(size_t)(o * 512 + chb + e) * 3 + tap]);
    }
    uint4 pk;
    pk.x = vals[0] | ((unsigned)vals[1] << 16);
    pk.y = vals[2] | ((unsigned)vals[3] << 16);
    pk.z = vals[4] | ((unsigned)vals[5] << 16);
    pk.w = vals[6] | ((unsigned)vals[7] << 16);
    *(uint4*)&dst[(size_t)rr * 8] = pk;
}

// ---------------- zero the halo rows (t=-1, t=T) of both padded buffers --------
__global__ void zero_pads(ushort_t* __restrict__ y1p, ushort_t* __restrict__ y2p) {
    int tid = blockIdx.x * blockDim.x + threadIdx.x;
    if (tid < 4096) {
        ushort_t* base = (tid & 1) ? y2p : y1p;
        int r = tid >> 1;
        int bb = r >> 7;
        int rowsel = (r >> 6) & 1;
        int col = (r & 63) * 8;
        size_t row = (size_t)bb * (T_ + 2) + (rowsel ? (T_ + 1) : 0);
        *(uint4*)&base[row * C_ + col] = (uint4){0, 0, 0, 0};
    }
}

// ---------------- win_sum(s) over t, output transposed: sw_t[b][t][s] bf16 ------
__global__ __launch_bounds__(256) void winsum_kernel(const float* __restrict__ s,
                                                     ushort_t* __restrict__ sw_t) {
    int b = blockIdx.y;
    int t0 = blockIdx.x * 64;
    __shared__ float sb[128][101];
    int tid = threadIdx.x;
    for (int e = tid; e < 128 * 100; e += 256) {
        int sj = e / 100;
        int u = e - sj * 100;
        int gt = t0 - HALF + u;
        float v = 0.f;
        if (gt >= 0 && gt < T_) v = s[((size_t)(b * S_ + sj)) * T_ + gt];
        sb[sj][u] = v;
    }
    __syncthreads();
    for (int e = tid; e < 64 * 128; e += 256) {
        int tl = e >> 7;
        int sj = e & 127;
        float sum = 0.f;
#pragma unroll
        for (int d = 0; d < WLEN; ++d) sum += sb[sj][tl + d];
        sw_t[((size_t)(b * T_ + t0 + tl)) * S_ + sj] = f2bf(sum);
    }
}

// ---------------- fused adawin instance + leaky-relu ----------------------------
template <int INLAYOUT>
__global__ __launch_bounds__(256) void adawin_kernel(
    const void* __restrict__ xin_, const ushort_t* __restrict__ sw_t,
    const ushort_t* __restrict__ Wfc, const float* __restrict__ fcb,
    const float* __restrict__ alpha, const int* __restrict__ lengths,
    ushort_t* __restrict__ youtp) {
    int t0 = blockIdx.x * 64;
    int c0 = blockIdx.y * 64;
    int b = blockIdx.z;
    __shared__ __attribute__((aligned(16))) ushort_t smem[128 * 136 + 64 * 136];
    ushort_t (*As)[136] = (ushort_t(*)[136])smem;
    ushort_t (*Bs)[136] = (ushort_t(*)[136])(smem + 128 * 136);
    int tid = threadIdx.x;

    {
        int r = tid >> 4;
        int cseg = (tid & 15) * 8;
#pragma unroll
        for (int p = 0; p < 8; ++p) {
            int row = p * 16 + r;
            int grow = (row < 64) ? (c0 + row) : (448 + c0 + row);
            *(uint4*)&As[row][cseg] = *(const uint4*)&Wfc[(size_t)grow * 128 + cseg];
        }
    }
    {
        int tl = tid & 63;
        int sg = tid >> 6;
        const ushort_t* src = &sw_t[((size_t)(b * T_ + t0 + tl)) * S_];
#pragma unroll
        for (int j = 0; j < 4; ++j) {
            int col = sg * 32 + j * 8;
            *(uint4*)&Bs[tl][col] = *(const uint4*)&src[col];
        }
    }
    __syncthreads();

    int wave = tid >> 6, lane = tid & 63;
    int quad = lane >> 4, l = lane & 15;
    f32x4 accg[4], accb[4];
#pragma unroll
    for (int n = 0; n < 4; ++n) {
        accg[n] = (f32x4){0.f, 0.f, 0.f, 0.f};
        accb[n] = (f32x4){0.f, 0.f, 0.f, 0.f};
    }
    int rg = wave * 16 + l;
    int rb = 64 + wave * 16 + l;
#pragma unroll
    for (int ks = 0; ks < 4; ++ks) {
        int kc = ks * 32 + quad * 8;
        bf16x8 ag = *(const bf16x8*)&As[rg][kc];
        bf16x8 ab = *(const bf16x8*)&As[rb][kc];
#pragma unroll
        for (int n = 0; n < 4; ++n) {
            bf16x8 bb = *(const bf16x8*)&Bs[n * 16 + l][kc];
            accg[n] = MFMA16(ag, bb, accg[n]);
            accb[n] = MFMA16(ab, bb, accb[n]);
        }
    }

    __syncthreads();
    ushort_t (*Ts)[72] = (ushort_t(*)[72])smem;

    int len = lengths[b];
    float alph = alpha[0];
    const float* xf = (const float*)xin_;
    const ushort_t* xh = (const ushort_t*)xin_;
    int clocal = wave * 16 + quad * 4;
    int cbase = c0 + clocal;
#pragma unroll
    for (int n = 0; n < 4; ++n) {
        int t = t0 + n * 16 + l;
        int lo = t - HALF; if (lo < 0) lo = 0;
        int hi = t + HALF; if (hi > T_ - 1) hi = T_ - 1;
        float cnt = (float)(hi - lo + 1);
        int hv = hi < (len - 1) ? hi : (len - 1);
        int mdi = hv - lo + 1; if (mdi < 0) mdi = 0;
        float m = (t < len) ? 1.f : 0.f;
        float sc = m / ((float)mdi + 1e-9f);

        float xv[4];
        if (INLAYOUT == 0) {
#pragma unroll
            for (int j = 0; j < 4; ++j)
                xv[j] = xf[(size_t)(b * C_ + cbase + j) * T_ + t];
        } else {
            uint2 xraw = *(const uint2*)&xh[((size_t)(b * (T_ + 2) + 1 + t)) * C_ + cbase];
            xv[0] = bf2f((ushort_t)(xraw.x & 0xffff));
            xv[1] = bf2f((ushort_t)(xraw.x >> 16));
            xv[2] = bf2f((ushort_t)(xraw.y & 0xffff));
            xv[3] = bf2f((ushort_t)(xraw.y >> 16));
        }
        unsigned pk[2];
#pragma unroll
        for (int j = 0; j < 4; ++j) {
            int c = cbase + j;
            float gamma = (accg[n][j] + fcb[c] * cnt) * sc;
            float beta = (accb[n][j] + fcb[C_ + c] * cnt) * sc;
            float xn = fast_tanh(alph * xv[j]);
            float v = (1.f + gamma) * xn + beta;
            v = v > 0.f ? v : 0.2f * v;
            unsigned hv16 = (unsigned)f2bf(v);
            if (j & 1) pk[j >> 1] |= hv16 << 16;
            else pk[j >> 1] = hv16;
        }
        *(uint2*)&Ts[n * 16 + l][clocal] = (uint2){pk[0], pk[1]};
    }
    __syncthreads();
    {
        int row = tid >> 2;
        int seg = (tid & 3) * 16;
        size_t gbase = ((size_t)(b * (T_ + 2) + 1 + t0 + row)) * C_ + c0 + seg;
        *(uint4*)&youtp[gbase] = *(const uint4*)&Ts[row][seg];
        *(uint4*)&youtp[gbase + 8] = *(const uint4*)&Ts[row][seg + 8];
    }
}

// ---------------- conv1d k=3: MFMA implicit GEMM, async glds double-buffer ------
// LDS A = pre-built weight image [128][104] (13x16B granules, odd -> 8 bank grps)
// LDS B = [134][40] (5 granules, odd). 37 glds spans/chunk split across 4 waves.
#define A_BYTES 26624  // 26 x 1024
#define B_BYTES 11264  // 11 x 1024
__device__ __forceinline__ void conv_stage(const char* aimg, const char* xt, int ch,
                                           char* Ab, char* Bb, int wave, int lane) {
#pragma unroll
    for (int i = 0; i < 37; ++i) {
        if ((i & 3) != wave) continue;
        if (i < 26) {
            glds16(aimg + i * 1024 + lane * 16, Ab + i * 1024);
        } else {
            int j = i - 26;
            int gi = j * 64 + lane;           // granule index in B tile
            int r = gi / 5;
            int gg = gi - r * 5;
            if (gg == 4) gg = 0;              // pad granule: clamp to valid addr
            glds16(xt + (size_t)r * 1024 + ch * 64 + gg * 16, Bb + j * 1024);
        }
    }
}

template <int EPI>
__global__ __launch_bounds__(256) void conv_kernel(
    const ushort_t* __restrict__ Xp, const ushort_t* __restrict__ Wimg,
    const float* __restrict__ bias, const float* __restrict__ resid,
    ushort_t* __restrict__ out_bf, float* __restrict__ out_f) {
    int t0 = blockIdx.x * 128;
    int o0 = blockIdx.y * 128;
    int b = blockIdx.z;
    __shared__ __attribute__((aligned(16))) char smembuf[2 * A_BYTES + 2 * B_BYTES];
    int tid = threadIdx.x;
    int lane = tid & 63, wave = tid >> 6;
    int l32 = lane & 31, khalf = lane >> 5;
    int wo = (wave & 1) * 64, wt = (wave >> 1) * 64;

    const char* imgbase = (const char*)Wimg + (size_t)blockIdx.y * 16 * A_BYTES;
    const char* xt = (const char*)Xp + (size_t)(b * (T_ + 2) + t0) * 1024;  // row r <-> t0-1+r

    f32x16 acc[2][2];
#pragma unroll
    for (int io = 0; io < 2; ++io)
#pragma unroll
        for (int it = 0; it < 2; ++it)
#pragma unroll
            for (int r = 0; r < 16; ++r) acc[io][it][r] = 0.f;

    conv_stage(imgbase, xt, 0, smembuf, smembuf + 2 * A_BYTES, wave, lane);
    asm volatile("s_waitcnt vmcnt(0)" ::: "memory");
    __syncthreads();

#pragma unroll 1
    for (int ch = 0; ch < 16; ++ch) {
        int cur = ch & 1;
        if (ch < 15)
            conv_stage(imgbase + (size_t)(ch + 1) * A_BYTES, xt, ch + 1,
                       smembuf + (cur ^ 1) * A_BYTES,
                       smembuf + 2 * A_BYTES + (cur ^ 1) * B_BYTES, wave, lane);
        ushort_t (*As)[104] = (ushort_t(*)[104])(smembuf + cur * A_BYTES);
        ushort_t (*Bs)[40] = (ushort_t(*)[40])(smembuf + 2 * A_BYTES + cur * B_BYTES);
#pragma unroll
        for (int tap = 0; tap < 3; ++tap) {
#pragma unroll
            for (int ks = 0; ks < 2; ++ks) {
                int kc = tap * 32 + ks * 16 + khalf * 8;
                bf16x8 a0 = *(const bf16x8*)&As[wo + l32][kc];
                bf16x8 a1 = *(const bf16x8*)&As[wo + 32 + l32][kc];
#pragma unroll
                for (int it = 0; it < 2; ++it) {
                    bf16x8 bb =
                        *(const bf16x8*)&Bs[wt + it * 32 + l32 + tap][ks * 16 + khalf * 8];
                    acc[0][it] = MFMA32(a0, bb, acc[0][it]);
                    acc[1][it] = MFMA32(a1, bb, acc[1][it]);
                }
            }
        }
        asm volatile("s_waitcnt vmcnt(0)" ::: "memory");
        __syncthreads();
    }

    // epilogue: C/D layout col=lane&31 (t), row=(reg&3)+8*(reg>>2)+4*khalf (o)
    if (EPI == 0) {
        ushort_t (*Ts)[136] = (ushort_t(*)[136])smembuf;  // 34816 B fits
#pragma unroll
        for (int io = 0; io < 2; ++io)
#pragma unroll
            for (int it = 0; it < 2; ++it) {
                int trow = wt + it * 32 + l32;
#pragma unroll
                for (int g = 0; g < 4; ++g) {
                    int oc = wo + io * 32 + g * 8 + khalf * 4;
                    unsigned pk[2];
#pragma unroll
                    for (int j = 0; j < 4; ++j) {
                        float v = acc[io][it][g * 4 + j] + bias[o0 + oc + j];
                        unsigned hv16 = (unsigned)f2bf(v);
                        if (j & 1) pk[j >> 1] |= hv16 << 16;
                        else pk[j >> 1] = hv16;
                    }
                    *(uint2*)&Ts[trow][oc] = (uint2){pk[0], pk[1]};
                }
            }
        __syncthreads();
        int cc = (tid & 15) * 8;
        int rbse = tid >> 4;
#pragma unroll
        for (int j = 0; j < 8; ++j) {
            int row = j * 16 + rbse;
            *(uint4*)&out_bf[((size_t)(b * (T_ + 2) + 1 + t0 + row)) * C_ + o0 + cc] =
                *(const uint4*)&Ts[row][cc];
        }
    } else {
#pragma unroll
        for (int io = 0; io < 2; ++io)
#pragma unroll
            for (int it = 0; it < 2; ++it) {
                int obase = o0 + wo + io * 32;
                int t = t0 + wt + it * 32 + l32;
#pragma unroll
                for (int g = 0; g < 4; ++g) {
                    int oo = obase + g * 8 + khalf * 4;
#pragma unroll
                    for (int j = 0; j < 4; ++j) {
                        size_t off = (size_t)(b * C_ + oo + j) * T_ + t;
                        out_f[off] = (acc[io][it][g * 4 + j] + bias[oo + j] + resid[off]) *
                                     0.70710678118654752f;
                    }
                }
            }
    }
}

extern "C" void kernel_launch(void* const* d_in, const int* in_sizes, int n_in,
                              void* d_out, int out_size, void* d_ws, size_t ws_size,
                              hipStream_t stream) {
    const float* x = (const float*)d_in[0];
    const float* s = (const float*)d_in[1];
    const int* lengths = (const int*)d_in[2];
    const float* fc1_w = (const float*)d_in[3];
    const float* fc1_b = (const float*)d_in[4];
    const float* alpha1 = (const float*)d_in[5];
    const float* conv1_w = (const float*)d_in[6];
    const float* conv1_b = (const float*)d_in[7];
    const float* fc2_w = (const float*)d_in[8];
    const float* fc2_b = (const float*)d_in[9];
    const float* alpha2 = (const float*)d_in[10];
    const float* conv2_w = (const float*)d_in[11];
    const float* conv2_b = (const float*)d_in[12];

    const size_t IMG = (size_t)4 * 16 * 1664 * 8;  // halfs per conv image
    char* ws = (char*)d_ws;
    ushort_t* sw_t = (ushort_t*)ws; ws += (size_t)B_ * T_ * S_ * 2;        // 8 MB
    ushort_t* Wfc = (ushort_t*)ws;  ws += (size_t)2 * 1024 * 128 * 2;      // 0.5 MB
    ushort_t* I1 = (ushort_t*)ws;   ws += IMG * 2;                         // 1.7 MB
    ushort_t* I2 = (ushort_t*)ws;   ws += IMG * 2;                         // 1.7 MB
    ushort_t* y2p = (ushort_t*)ws;  ws += (size_t)B_ * (T_ + 2) * C_ * 2;  // 33.6 MB
    ushort_t* y1p = (ushort_t*)ws;  ws += (size_t)B_ * (T_ + 2) * C_ * 2;  // 33.6 MB (last:
    ws += 12 * 1024;  // glds over-read slack (conv input is always y1p)
    if ((size_t)(ws - (char*)d_ws) > ws_size) return;

    prep_weights<<<dim3(1024), dim3(256), 0, stream>>>(fc1_w, fc2_w, Wfc);
    prep_conv_images<<<dim3(832), dim3(256), 0, stream>>>(conv1_w, conv2_w, I1, I2);
    winsum_kernel<<<dim3(32, 16), dim3(256), 0, stream>>>(s, sw_t);
    zero_pads<<<dim3(16), dim3(256), 0, stream>>>(y1p, y2p);
    adawin_kernel<0><<<dim3(32, 8, 16), dim3(256), 0, stream>>>(
        (const void*)x, sw_t, Wfc, fc1_b, alpha1, lengths, y1p);
    conv_kernel<0><<<dim3(16, 4, 16), dim3(256), 0, stream>>>(
        y1p, I1, conv1_b, (const float*)nullptr, y2p, (float*)nullptr);
    adawin_kernel<1><<<dim3(32, 8, 16), dim3(256), 0, stream>>>(
        (const void*)y2p, sw_t, Wfc + 1024 * 128, fc2_b, alpha2, lengths, y1p);
    conv_kernel<1><<<dim3(16, 4, 16), dim3(256), 0, stream>>>(
        y1p, I2, conv2_b, x, (ushort_t*)nullptr, (float*)d_out);
}